// Round 8
// baseline (58.959 us; speedup 1.0000x reference)
//
#include <hip/hip_runtime.h>
#include <math.h>

#define BATCH 64
#define MM 100     // predictions per batch (columns)
#define NN 100     // targets per batch (rows after compaction)
#define ST 101     // padded LDS stride (conflict-free row scans)
#define BIGCLAIM 0x7fffffff
#define WS_STATE_OFF 512
#define WS_STRIDE   1024
// per-batch state layout (ints): [0]=K, [2..3]=dijA, [4..5]=dijB,
// [6..106]=p[101], then float vv[101]

// ---------- wave-uniform primitives (VALU, not LDS pipe) ----------

__device__ __forceinline__ int readlane_i(int v, int lane) {
    return __builtin_amdgcn_readlane(v, lane);
}
__device__ __forceinline__ float readlane_f(float v, int lane) {
    return __int_as_float(__builtin_amdgcn_readlane(__float_as_int(v), lane));
}

// order-preserving float->u32 map; pack 7-bit column index into low bits.
// Truncates 7 mantissa LSBs for selection only (exact values re-read via
// readlane); ties break to lowest column = numpy argmin semantics.
__device__ __forceinline__ unsigned pack_key(float x, int col) {
    unsigned u = __float_as_uint(x);
    u ^= ((unsigned)((int)u >> 31)) | 0x80000000u;
    return (u & 0xFFFFFF80u) | (unsigned)col;
}

template<int CTRL>
__device__ __forceinline__ unsigned dpp_min_u32(unsigned x) {
    int p = __builtin_amdgcn_update_dpp((int)x, (int)x, CTRL, 0xF, 0xF, false);
    unsigned up = (unsigned)p;
    return (x < up) ? x : up;
}
// full-wave64 min broadcast (6 DPP umin steps): returns min(key) wave-wide
__device__ __forceinline__ unsigned wave_min_u32(unsigned x) {
    x = dpp_min_u32<0xB1>(x);    // quad_perm xor1
    x = dpp_min_u32<0x4E>(x);    // quad_perm xor2
    x = dpp_min_u32<0x141>(x);   // row_half_mirror
    x = dpp_min_u32<0x140>(x);   // row_mirror
    x = dpp_min_u32<0x142>(x);   // row_bcast15
    x = dpp_min_u32<0x143>(x);   // row_bcast31
    return (unsigned)readlane_i((int)x, 63);
}

// ============ stage 1: build + greedy claim + ARR -> state in ws ============
__global__ __launch_bounds__(128) void hung_stage1(
        const float* __restrict__ pred, const float* __restrict__ target,
        char* __restrict__ wsbase) {
    const int b    = blockIdx.x;
    const int tid  = threadIdx.x;
    const int lane = tid & 63;
    const int wave = tid >> 6;
    const float* P = pred + b * MM * 3;
    const float* T = target + b * NN * 3;

    __shared__ float tvx[NN], tvy[NN];
    __shared__ float Tc[NN * ST];
    __shared__ int   rmini[NN];
    __shared__ int   claimArr[MM + 1];
    __shared__ int   Ksh;

    float pxA = P[3*lane], pyA = P[3*lane+1];
    float pxB = 0.f, pyB = 0.f;
    const bool colBvalid = (lane + 64 < MM);
    if (colBvalid) { pxB = P[3*(lane+64)]; pyB = P[3*(lane+64)+1]; }

    int* st = (int*)(wsbase + WS_STATE_OFF + (size_t)b * WS_STRIDE);

    if (wave == 0) {
        float cxA=T[3*lane], cyA=T[3*lane+1], ccA=T[3*lane+2];
        bool vA_ = ccA > 0.5f;
        float cxB=0.f, cyB=0.f; bool vB_=false;
        if (lane + 64 < NN) {
            cxB=T[3*(lane+64)]; cyB=T[3*(lane+64)+1];
            vB_ = T[3*(lane+64)+2] > 0.5f;
        }
        unsigned long long mAv = __ballot(vA_);
        unsigned long long mBv = __ballot(vB_);
        int nA_ = __popcll(mAv);
        int K0  = nA_ + __popcll(mBv);
        unsigned long long below = (1ull << lane) - 1ull;
        if (vA_) { int q = __popcll(mAv & below);       tvx[q]=cxA; tvy[q]=cyA; }
        if (vB_) { int q = nA_ + __popcll(mBv & below); tvx[q]=cxB; tvy[q]=cyB; }
        if (lane == 0) Ksh = K0;
        claimArr[lane] = BIGCLAIM;
        if (lane + 64 <= MM) claimArr[lane + 64] = BIGCLAIM;
    }
    __syncthreads();
    const int K = Ksh;
    if (K == 0) { if (tid == 0) st[0] = 0; return; }

    float txA = (lane < K)      ? tvx[lane]      : 0.f;
    float tyA = (lane < K)      ? tvy[lane]      : 0.f;
    float txB = (lane + 64 < K) ? tvx[lane + 64] : 0.f;
    float tyB = (lane + 64 < K) ? tvy[lane + 64] : 0.f;

    // ---- cost build (waves split rows) + fused packed row argmin ----
    for (int c = wave; c < K; c += 2) {
        float tx = (c < 64) ? readlane_f(txA, c) : readlane_f(txB, c - 64);
        float ty = (c < 64) ? readlane_f(tyA, c) : readlane_f(tyB, c - 64);
        float dxA = __fsub_rn(pxA, tx), dyA = __fsub_rn(pyA, ty);
        float cA = __fsqrt_rn(__fadd_rn(__fmul_rn(dxA,dxA), __fmul_rn(dyA,dyA)));
        Tc[c*ST + lane] = cA;
        unsigned kB = 0xFFFFFFFFu;
        if (colBvalid) {
            float dxB = __fsub_rn(pxB, tx), dyB = __fsub_rn(pyB, ty);
            float cB = __fsqrt_rn(__fadd_rn(__fmul_rn(dxB,dxB), __fmul_rn(dyB,dyB)));
            Tc[c*ST + lane + 64] = cB;
            kB = pack_key(cB, lane + 64);
        }
        unsigned kA = pack_key(cA, lane);
        unsigned k = wave_min_u32(kA < kB ? kA : kB);
        if (lane == 0) rmini[c] = (int)(k & 127u);
    }
    __syncthreads();
    if (wave == 1) return;

    // ================== wave 0 only ==================
    const float INF32 = __builtin_inff();
    const int jA = lane;                 // column 0..63 (0 = sentinel)
    const int jB = lane + 64;            // column 64..127; valid if <= 100
    const bool validB = (jB <= MM);
    const int idxA = (jA >= 1) ? (jA - 1) : 0;
    const int idxB = validB ? (jB - 1) : (MM - 1);

    // ---- greedy claim: min row index wins each argmin column ----
    int rA = lane + 1, rB = lane + 65;
    int argA = 0, argB = 0;
    if (lane < K)      { argA = rmini[lane] + 1;      atomicMin(&claimArr[argA], rA); }
    if (lane + 64 < K) { argB = rmini[lane + 64] + 1; atomicMin(&claimArr[argB], rB); }
    __threadfence_block();
    int pA = 0, pB = 0;
    if (jA >= 1) { int c0 = claimArr[jA]; pA = (c0 != BIGCLAIM) ? c0 : 0; }
    if (validB)  { int c0 = claimArr[jB]; pB = (c0 != BIGCLAIM) ? c0 : 0; }
    bool freeA = (lane < K)      && (claimArr[argA] != rA);
    bool freeB = (lane + 64 < K) && (claimArr[argB] != rB);
    unsigned long long fA = __ballot(freeA);
    unsigned long long fB = __ballot(freeB);

    float vvA = 0.f, vvB = 0.f;

    // ---- JV augmenting row reduction, 2 sweeps (packed argmin) ----
    unsigned long long dijA = 0ull, dijB = 0ull;
    for (int sweep = 0; sweep < 2; ++sweep) {
        unsigned long long curA = fA, curB = fB;
        fA = 0ull; fB = 0ull;
        while (curA | curB) {
            int r;
            if (curA) { r = (int)__ffsll(curA);      curA &= curA - 1; }
            else      { r = (int)__ffsll(curB) + 64; curB &= curB - 1; }

            float cA = Tc[(r-1)*ST + idxA];
            float cB = Tc[(r-1)*ST + idxB];
            float rcA = (jA >= 1) ? (cA - vvA) : INF32;
            float rcB = validB ? (cB - vvB) : INF32;
            unsigned kA = pack_key(rcA, jA);
            unsigned kB = pack_key(rcB, jB);
            unsigned k1 = wave_min_u32(kA < kB ? kA : kB);
            int j1 = (int)(k1 & 127u);
            unsigned kA2 = (jA == j1) ? 0xFFFFFFFFu : kA;
            unsigned kB2 = (jB == j1) ? 0xFFFFFFFFu : kB;
            unsigned k2 = wave_min_u32(kA2 < kB2 ? kA2 : kB2);
            int j2 = (int)(k2 & 127u);

            float v1a = readlane_f(rcA, j1 & 63), v1b = readlane_f(rcB, j1 & 63);
            float val1 = (j1 < 64) ? v1a : v1b;
            float v2a = readlane_f(rcA, j2 & 63), v2b = readlane_f(rcB, j2 & 63);
            float val2 = (j2 < 64) ? v2a : v2b;
            float dv = fmaxf(val2 - val1, 0.f);

            int holder = (j1 < 64) ? readlane_i(pA, j1) : readlane_i(pB, j1 & 63);
            if (jA == j1) { vvA -= dv; pA = r; }
            if (validB && jB == j1) { vvB -= dv; pB = r; }
            if (holder != 0) {
                if (sweep == 0) {
                    if (holder <= 64) fA |= 1ull << (holder - 1);
                    else              fB |= 1ull << (holder - 65);
                } else {
                    if (holder <= 64) dijA |= 1ull << (holder - 1);
                    else              dijB |= 1ull << (holder - 65);
                }
            }
        }
    }

    // ---- persist state ----
    if (lane == 0) {
        st[0] = K;
        *(unsigned long long*)(st + 2) = dijA;
        *(unsigned long long*)(st + 4) = dijB;
    }
    int*   pArr  = st + 6;
    float* vvArr = (float*)(st + 6 + 101);
    pArr[lane] = pA;  vvArr[lane] = vvA;
    if (validB) { pArr[jB] = pB; vvArr[jB] = vvB; }
}

// ============ stage 2: rebuild Tc + Dijkstra + loss ============
__global__ __launch_bounds__(128) void hung_stage2(
        const float* __restrict__ pred, const float* __restrict__ target,
        char* __restrict__ wsbase, double* __restrict__ wsloss) {
    const int b    = blockIdx.x;
    const int tid  = threadIdx.x;
    const int lane = tid & 63;
    const int wave = tid >> 6;
    const float* P = pred + b * MM * 3;
    const float* T = target + b * NN * 3;

    __shared__ float px[MM], py[MM], pc[MM];
    __shared__ float tvx[NN], tvy[NN], tvc[NN];
    __shared__ float Tc[NN * ST];
    __shared__ int   Ksh;

    float pxA = P[3*lane], pyA = P[3*lane+1];
    float pxB = 0.f, pyB = 0.f;
    const bool colBvalid = (lane + 64 < MM);
    if (colBvalid) { pxB = P[3*(lane+64)]; pyB = P[3*(lane+64)+1]; }

    const int* st = (const int*)(wsbase + WS_STATE_OFF + (size_t)b * WS_STRIDE);

    if (wave == 0) {
        px[lane] = pxA; py[lane] = pyA; pc[lane] = P[3*lane+2];
        if (colBvalid) { px[lane+64]=pxB; py[lane+64]=pyB; pc[lane+64]=P[3*(lane+64)+2]; }
        float cxA=T[3*lane], cyA=T[3*lane+1], ccA=T[3*lane+2];
        bool vA_ = ccA > 0.5f;
        float cxB=0.f, cyB=0.f, ccB=0.f; bool vB_=false;
        if (lane + 64 < NN) {
            cxB=T[3*(lane+64)]; cyB=T[3*(lane+64)+1]; ccB=T[3*(lane+64)+2];
            vB_ = ccB > 0.5f;
        }
        unsigned long long mAv = __ballot(vA_);
        unsigned long long mBv = __ballot(vB_);
        int nA_ = __popcll(mAv);
        int K0  = nA_ + __popcll(mBv);
        unsigned long long below = (1ull << lane) - 1ull;
        if (vA_) { int q = __popcll(mAv & below);       tvx[q]=cxA; tvy[q]=cyA; tvc[q]=ccA; }
        if (vB_) { int q = nA_ + __popcll(mBv & below); tvx[q]=cxB; tvy[q]=cyB; tvc[q]=ccB; }
        if (lane == 0) Ksh = K0;
    }
    __syncthreads();
    const int K = Ksh;
    if (K == 0) { if (tid == 0) wsloss[b] = 0.0; return; }

    float txA = (lane < K)      ? tvx[lane]      : 0.f;
    float tyA = (lane < K)      ? tvy[lane]      : 0.f;
    float txB = (lane + 64 < K) ? tvx[lane + 64] : 0.f;
    float tyB = (lane + 64 < K) ? tvy[lane + 64] : 0.f;

    // ---- early-issue state loads (hide under build) ----
    const int jA = lane;
    const int jB = lane + 64;
    const bool validB = (jB <= MM);
    unsigned long long dijA = *(const unsigned long long*)(st + 2);
    unsigned long long dijB = *(const unsigned long long*)(st + 4);
    const int*   pArr  = st + 6;
    const float* vvArr = (const float*)(st + 6 + 101);
    int pA = pArr[lane];
    int pB = validB ? pArr[jB] : 0;
    float vvA = vvArr[lane];
    float vvB = validB ? vvArr[jB] : 0.f;

    // ---- rebuild cost matrix (waves split rows) ----
    for (int c = wave; c < K; c += 2) {
        float tx = (c < 64) ? readlane_f(txA, c) : readlane_f(txB, c - 64);
        float ty = (c < 64) ? readlane_f(tyA, c) : readlane_f(tyB, c - 64);
        float dxA = __fsub_rn(pxA, tx), dyA = __fsub_rn(pyA, ty);
        Tc[c*ST + lane] = __fsqrt_rn(__fadd_rn(__fmul_rn(dxA,dxA), __fmul_rn(dyA,dyA)));
        if (colBvalid) {
            float dxB = __fsub_rn(pxB, tx), dyB = __fsub_rn(pyB, ty);
            Tc[c*ST + lane + 64] = __fsqrt_rn(__fadd_rn(__fmul_rn(dxB,dxB), __fmul_rn(dyB,dyB)));
        }
    }
    __syncthreads();
    if (wave == 1) return;

    // ================== wave 0: Dijkstra phases ==================
    const float INF32 = __builtin_inff();
    const int idxA = (jA >= 1) ? (jA - 1) : 0;
    const int idxB = validB ? (jB - 1) : (MM - 1);

    while (dijA | dijB) {
        int r;
        if (dijA) { r = (int)__ffsll(dijA);      dijA &= dijA - 1; }
        else      { r = (int)__ffsll(dijB) + 64; dijB &= dijB - 1; }

        float minvA = INF32, minvB = INF32;
        int wayA = 0, wayB = 0;
        bool usedA = (lane == 0), usedB = false;
        float dpopA = 0.f, dpopB = 0.f;
        if (lane == 0) pA = r;           // p[0] = r (augment terminator)
        int j0 = 0, jfree = -1;
        float dstar = 0.f;

        float cA_f = Tc[(r-1)*ST + idxA];
        float cB_f = Tc[(r-1)*ST + idxB];
        float S = 0.f;                   // u0 arbitrary (uniform shift)

        for (int it = 0; it <= MM; ++it) {
            if (jA >= 1 && !usedA) {
                float t = (cA_f - vvA) + S;
                if (t < minvA) { minvA = t; wayA = j0; }
            }
            if (validB && !usedB) {
                float t = (cB_f - vvB) + S;
                if (t < minvB) { minvB = t; wayB = j0; }
            }
            unsigned kA = (jA >= 1 && !usedA) ? pack_key(minvA, jA) : 0xFFFFFFFFu;
            unsigned kB = (validB && !usedB) ? pack_key(minvB, jB) : 0xFFFFFFFFu;
            unsigned k1 = wave_min_u32(kA < kB ? kA : kB);
            int j1 = (int)(k1 & 127u);
            float da = readlane_f(minvA, j1 & 63), db = readlane_f(minvB, j1 & 63);
            float delta = (j1 < 64) ? da : db;

            if (jA == j1) { usedA = true; dpopA = delta; }
            if (jB == j1) { usedB = true; dpopB = delta; }

            int pa = readlane_i(pA, j1 & 63);
            int pb = readlane_i(pB, j1 & 63);
            int pj1 = (j1 < 64) ? pa : pb;
            if (pj1 == 0) { jfree = j1; dstar = delta; break; }

            float nxA = Tc[(pj1-1)*ST + idxA];
            float nxB = Tc[(pj1-1)*ST + idxB];
            float cjm = (j1 < 64) ? readlane_f(nxA, j1) : readlane_f(nxB, j1 & 63);
            float vjm = (j1 < 64) ? readlane_f(vvA, j1) : readlane_f(vvB, j1 & 63);
            S = (delta - cjm) + vjm;
            cA_f = nxA; cB_f = nxB;
            j0 = j1;
        }

        if (usedA && jA >= 1) vvA += dpopA - dstar;
        if (usedB)            vvB += dpopB - dstar;

        int jc = jfree;
        for (int s = 0; s <= MM && jc > 0; ++s) {
            int wa = readlane_i(wayA, jc & 63);
            int wb = readlane_i(wayB, jc & 63);
            int w  = (jc < 64) ? wa : wb;
            int pa = readlane_i(pA, w & 63);
            int pb = readlane_i(pB, w & 63);
            int pw = (w < 64) ? pa : pb;
            if (jA == jc) pA = pw;
            if (jB == jc) pB = pw;
            jc = w;
        }
    }

    // ---- loss (f64, matches reference arithmetic) ----
    double se = 0.0, bce = 0.0;
    if (jA >= 1 && pA > 0) {
        int rr = jA - 1, c = pA - 1;
        float dx = __fsub_rn(px[rr], tvx[c]);
        float dy = __fsub_rn(py[rr], tvy[c]);
        se = (double)dx*(double)dx + (double)dy*(double)dy;
        double pcv = (double)pc[rr];
        pcv = fmin(fmax(pcv, 1e-12), 1.0 - 1e-12);
        double tc = (double)tvc[c];
        bce = -(tc * log(pcv) + (1.0 - tc) * log1p(-pcv));
    }
    if (validB && pB > 0) {
        int rr = jB - 1, c = pB - 1;
        float dx = __fsub_rn(px[rr], tvx[c]);
        float dy = __fsub_rn(py[rr], tvy[c]);
        se += (double)dx*(double)dx + (double)dy*(double)dy;
        double pcv = (double)pc[rr];
        pcv = fmin(fmax(pcv, 1e-12), 1.0 - 1e-12);
        double tc = (double)tvc[c];
        bce += -(tc * log(pcv) + (1.0 - tc) * log1p(-pcv));
    }
    for (int m = 1; m < 64; m <<= 1) {
        se  += __shfl_xor(se,  m, 64);
        bce += __shfl_xor(bce, m, 64);
    }
    if (lane == 0) wsloss[b] = se / (2.0 * (double)K) + bce / (double)K;
}

__global__ __launch_bounds__(64) void final_reduce(const double* __restrict__ ws,
                                                   float* __restrict__ out) {
    double v = ws[threadIdx.x];   // BATCH == 64 == one wave
    for (int m = 1; m < 64; m <<= 1) v += __shfl_xor(v, m, 64);
    if (threadIdx.x == 0) out[0] = (float)(v / (double)BATCH);
}

extern "C" void kernel_launch(void* const* d_in, const int* in_sizes, int n_in,
                              void* d_out, int out_size, void* d_ws, size_t ws_size,
                              hipStream_t stream) {
    const float* pred   = (const float*)d_in[0];
    const float* target = (const float*)d_in[1];
    char*   wsb = (char*)d_ws;
    double* wsl = (double*)d_ws;
    float*  out = (float*)d_out;
    hung_stage1<<<dim3(BATCH), dim3(128), 0, stream>>>(pred, target, wsb);
    hung_stage2<<<dim3(BATCH), dim3(128), 0, stream>>>(pred, target, wsb, wsl);
    final_reduce<<<dim3(1), dim3(64), 0, stream>>>(wsl, out);
}

// Round 9
// 56.401 us; speedup vs baseline: 1.0454x; 1.0454x over previous
//
#include <hip/hip_runtime.h>
#include <math.h>

#define BATCH 64
#define MM 100     // predictions per batch (columns)
#define NN 100     // targets per batch (rows after compaction)
#define ST 101     // padded LDS stride (conflict-free row scans)
#define BIGCLAIM 0x7fffffff
#define SENTK 0xFFFFFFFFu

// ---------- wave-uniform primitives ----------

__device__ __forceinline__ int readlane_i(int v, int lane) {
    return __builtin_amdgcn_readlane(v, lane);
}
__device__ __forceinline__ float readlane_f(float v, int lane) {
    return __int_as_float(__builtin_amdgcn_readlane(__float_as_int(v), lane));
}

// order-preserving float->u32 key; low 7 bits = column index. Truncation
// (127 ulp, ~2^-17 rel) only perturbs near-ties; key_val(k) <= true value.
__device__ __forceinline__ unsigned pack_key(float x, int col) {
    unsigned u = __float_as_uint(x);
    u ^= ((unsigned)((int)u >> 31)) | 0x80000000u;
    return (u & 0xFFFFFF80u) | (unsigned)col;
}
__device__ __forceinline__ float key_val(unsigned k) {
    unsigned u = k & 0xFFFFFF80u;
    u = (u & 0x80000000u) ? (u ^ 0x80000000u) : ~u;
    return __uint_as_float(u);
}

template<int CTRL>
__device__ __forceinline__ unsigned dpp_mov_u32(unsigned x) {
    return (unsigned)__builtin_amdgcn_update_dpp((int)x, (int)x, CTRL, 0xF, 0xF, false);
}
template<int CTRL>
__device__ __forceinline__ unsigned dpp_min_u32(unsigned x) {
    unsigned p = dpp_mov_u32<CTRL>(x);
    return x < p ? x : p;
}
// full-wave64 min broadcast (valid at lane 63; path covers all lanes)
__device__ __forceinline__ unsigned wave_min_u32(unsigned x) {
    x = dpp_min_u32<0xB1>(x);
    x = dpp_min_u32<0x4E>(x);
    x = dpp_min_u32<0x141>(x);
    x = dpp_min_u32<0x140>(x);
    x = dpp_min_u32<0x142>(x);
    x = dpp_min_u32<0x143>(x);
    return (unsigned)readlane_i((int)x, 63);
}
// two smallest keys across the wave (each lane contributes 2 candidates).
// Lane 63's (lo,hi) merges only disjoint coverage sets -> correct there.
template<int CTRL>
__device__ __forceinline__ void min2_step(unsigned &lo, unsigned &hi) {
    unsigned olo = dpp_mov_u32<CTRL>(lo);
    unsigned ohi = dpp_mov_u32<CTRL>(hi);
    unsigned mn  = lo < olo ? lo : olo;
    unsigned mx  = lo < olo ? olo : lo;
    unsigned m2  = hi < ohi ? hi : ohi;
    lo = mn;
    hi = mx < m2 ? mx : m2;
}
__device__ __forceinline__ void wave_min2_u32(unsigned a, unsigned b,
                                              unsigned &k1, unsigned &k2) {
    unsigned lo = a < b ? a : b;
    unsigned hi = a < b ? b : a;
    min2_step<0xB1>(lo, hi);
    min2_step<0x4E>(lo, hi);
    min2_step<0x141>(lo, hi);
    min2_step<0x140>(lo, hi);
    min2_step<0x142>(lo, hi);
    min2_step<0x143>(lo, hi);
    k1 = (unsigned)readlane_i((int)lo, 63);
    k2 = (unsigned)readlane_i((int)hi, 63);
}

// One block (2 waves) per batch. Wave-parallel transposed JV: greedy claim
// (LDS atomicMin) -> 2 ARR sweeps (fused 2-min reduce, row prefetch) ->
// Dijkstra phases (implicit u, matched-edge-cost registers keep the S
// update off the LDS-load chain, phase-row prefetch). Last finished block
// sums all 64 losses and writes out[0] (device-scope atomics).

__global__ __launch_bounds__(128) void hung_all(
        const float* __restrict__ pred, const float* __restrict__ target,
        double* __restrict__ wsloss, unsigned* __restrict__ counter,
        float* __restrict__ out) {
    const int b    = blockIdx.x;
    const int tid  = threadIdx.x;
    const int lane = tid & 63;
    const int wave = tid >> 6;
    const float* P = pred + b * MM * 3;
    const float* T = target + b * NN * 3;

    __shared__ float px[MM], py[MM], pc[MM];
    __shared__ float tvx[NN], tvy[NN], tvc[NN];
    __shared__ float Tc[NN * ST];
    __shared__ int   rmini[NN];
    __shared__ int   claimArr[MM + 1];
    __shared__ int   Ksh;

    float pxA = P[3*lane], pyA = P[3*lane+1];
    float pxB = 0.f, pyB = 0.f;
    const bool colBvalid = (lane + 64 < MM);
    if (colBvalid) { pxB = P[3*(lane+64)]; pyB = P[3*(lane+64)+1]; }

    if (wave == 0) {
        px[lane] = pxA; py[lane] = pyA; pc[lane] = P[3*lane+2];
        if (colBvalid) { px[lane+64]=pxB; py[lane+64]=pyB; pc[lane+64]=P[3*(lane+64)+2]; }
        float cxA=T[3*lane], cyA=T[3*lane+1], ccA=T[3*lane+2];
        bool vA_ = ccA > 0.5f;
        float cxB=0.f, cyB=0.f, ccB=0.f; bool vB_=false;
        if (lane + 64 < NN) {
            cxB=T[3*(lane+64)]; cyB=T[3*(lane+64)+1]; ccB=T[3*(lane+64)+2];
            vB_ = ccB > 0.5f;
        }
        unsigned long long mAv = __ballot(vA_);
        unsigned long long mBv = __ballot(vB_);
        int nA_ = __popcll(mAv);
        int K0  = nA_ + __popcll(mBv);
        unsigned long long below = (1ull << lane) - 1ull;
        if (vA_) { int q = __popcll(mAv & below);       tvx[q]=cxA; tvy[q]=cyA; tvc[q]=ccA; }
        if (vB_) { int q = nA_ + __popcll(mBv & below); tvx[q]=cxB; tvy[q]=cyB; tvc[q]=ccB; }
        if (lane == 0) Ksh = K0;
        claimArr[lane] = BIGCLAIM;
        if (lane + 64 <= MM) claimArr[lane + 64] = BIGCLAIM;
    }
    __syncthreads();
    const int K = Ksh;

    const int jA = lane;                 // column 0..63 (0 = sentinel)
    const int jB = lane + 64;            // column 64..127; valid if <= 100
    const bool validB = (jB <= MM);
    const int idxA = (jA >= 1) ? (jA - 1) : 0;
    const int idxB = validB ? (jB - 1) : (MM - 1);

    double loss = 0.0;
    if (K > 0) {
        float txA = (lane < K)      ? tvx[lane]      : 0.f;
        float tyA = (lane < K)      ? tvy[lane]      : 0.f;
        float txB = (lane + 64 < K) ? tvx[lane + 64] : 0.f;
        float tyB = (lane + 64 < K) ? tvy[lane + 64] : 0.f;

        // ---- cost build (waves split rows) + fused packed row argmin ----
        for (int c = wave; c < K; c += 2) {
            float tx = (c < 64) ? readlane_f(txA, c) : readlane_f(txB, c - 64);
            float ty = (c < 64) ? readlane_f(tyA, c) : readlane_f(tyB, c - 64);
            float dxA = __fsub_rn(pxA, tx), dyA = __fsub_rn(pyA, ty);
            float cA = __fsqrt_rn(__fadd_rn(__fmul_rn(dxA,dxA), __fmul_rn(dyA,dyA)));
            Tc[c*ST + lane] = cA;
            unsigned kB = SENTK;
            if (colBvalid) {
                float dxB = __fsub_rn(pxB, tx), dyB = __fsub_rn(pyB, ty);
                float cB = __fsqrt_rn(__fadd_rn(__fmul_rn(dxB,dxB), __fmul_rn(dyB,dyB)));
                Tc[c*ST + lane + 64] = cB;
                kB = pack_key(cB, lane + 64);
            }
            unsigned kA = pack_key(cA, lane);
            unsigned k = wave_min_u32(kA < kB ? kA : kB);
            if (lane == 0) rmini[c] = (int)(k & 127u);
        }
        __syncthreads();
        if (wave == 1) return;

        // ---- greedy claim: min row index wins each argmin column ----
        int rA_ = lane + 1, rB_ = lane + 65;
        int argA = 0, argB = 0;
        if (lane < K)      { argA = rmini[lane] + 1;      atomicMin(&claimArr[argA], rA_); }
        if (lane + 64 < K) { argB = rmini[lane + 64] + 1; atomicMin(&claimArr[argB], rB_); }
        __threadfence_block();
        int pA = 0, pB = 0;
        if (jA >= 1) { int c0 = claimArr[jA]; pA = (c0 != BIGCLAIM) ? c0 : 0; }
        if (validB)  { int c0 = claimArr[jB]; pB = (c0 != BIGCLAIM) ? c0 : 0; }
        bool freeA = (lane < K)      && (claimArr[argA] != rA_);
        bool freeB = (lane + 64 < K) && (claimArr[argB] != rB_);
        unsigned long long fA = __ballot(freeA);
        unsigned long long fB = __ballot(freeB);

        // matched-edge cost registers
        float mcA = 0.f, mcB = 0.f;
        if (pA > 0) mcA = Tc[(pA-1)*ST + idxA];
        if (pB > 0) mcB = Tc[(pB-1)*ST + idxB];

        float vvA = 0.f, vvB = 0.f;

        // ---- ARR, 2 sweeps: fused 2-min reduce + next-row prefetch ----
        unsigned long long dijA = 0ull, dijB = 0ull;
        for (int sweep = 0; sweep < 2; ++sweep) {
            unsigned long long curA = fA, curB = fB;
            fA = 0ull; fB = 0ull;
            int rr = curA ? (int)__ffsll(curA)
                          : (curB ? (int)__ffsll(curB) + 64 : 0);
            float cA = 0.f, cB = 0.f;
            if (rr) { cA = Tc[(rr-1)*ST + idxA]; cB = Tc[(rr-1)*ST + idxB]; }
            while (curA | curB) {
                int r;
                if (curA) { r = (int)__ffsll(curA);      curA &= curA - 1; }
                else      { r = (int)__ffsll(curB) + 64; curB &= curB - 1; }
                int r2 = curA ? (int)__ffsll(curA)
                              : (curB ? (int)__ffsll(curB) + 64 : r);
                float nxA = Tc[(r2-1)*ST + idxA];     // prefetch next row
                float nxB = Tc[(r2-1)*ST + idxB];

                float rcA = cA - vvA;
                float rcB = cB - vvB;
                unsigned kA = (jA >= 1) ? pack_key(rcA, jA) : SENTK;
                unsigned kB = validB ? pack_key(rcB, jB) : SENTK;
                unsigned k1, k2;
                wave_min2_u32(kA, kB, k1, k2);
                int j1 = (int)(k1 & 127u);
                float dv = fmaxf(key_val(k2) - key_val(k1), 0.f);

                int holder = (j1 < 64) ? readlane_i(pA, j1)
                                       : readlane_i(pB, j1 & 63);
                if (jA == j1)            { vvA -= dv; pA = r; mcA = cA; }
                if (validB && jB == j1)  { vvB -= dv; pB = r; mcB = cB; }
                if (holder != 0) {
                    if (sweep == 0) {
                        if (holder <= 64) fA |= 1ull << (holder - 1);
                        else              fB |= 1ull << (holder - 65);
                    } else {
                        if (holder <= 64) dijA |= 1ull << (holder - 1);
                        else              dijB |= 1ull << (holder - 65);
                    }
                }
                cA = nxA; cB = nxB;
            }
        }

        // ---- Dijkstra phases (implicit u; S via mc/v readlanes only) ----
        const float INF32 = __builtin_inff();
        float pcAf = 0.f, pcBf = 0.f;
        {
            int r0 = dijA ? (int)__ffsll(dijA)
                          : (dijB ? (int)__ffsll(dijB) + 64 : 0);
            if (r0) { pcAf = Tc[(r0-1)*ST + idxA]; pcBf = Tc[(r0-1)*ST + idxB]; }
        }
        while (dijA | dijB) {
            int r;
            if (dijA) { r = (int)__ffsll(dijA);      dijA &= dijA - 1; }
            else      { r = (int)__ffsll(dijB) + 64; dijB &= dijB - 1; }

            float minvA = INF32, minvB = INF32;
            int wayA = 0, wayB = 0;
            bool usedA = (lane == 0), usedB = false;
            float dpopA = 0.f, dpopB = 0.f;
            if (lane == 0) pA = r;       // p[0] = r (augment terminator)
            int j0 = 0, jfree = -1;
            float dstar = 0.f, S = 0.f;
            float cA_f = pcAf, cB_f = pcBf;

            for (int it = 0; it <= MM; ++it) {
                if (jA >= 1 && !usedA) {
                    float t = (cA_f - vvA) + S;
                    if (t < minvA) { minvA = t; wayA = j0; }
                }
                if (validB && !usedB) {
                    float t = (cB_f - vvB) + S;
                    if (t < minvB) { minvB = t; wayB = j0; }
                }
                unsigned kA = (jA >= 1 && !usedA) ? pack_key(minvA, jA) : SENTK;
                unsigned kB = (validB && !usedB) ? pack_key(minvB, jB) : SENTK;
                unsigned k1 = wave_min_u32(kA < kB ? kA : kB);
                int j1 = (int)(k1 & 127u);
                float delta = key_val(k1);

                if (jA == j1) { usedA = true; dpopA = delta; }
                if (jB == j1) { usedB = true; dpopB = delta; }

                int pj1 = (j1 < 64) ? readlane_i(pA, j1)
                                    : readlane_i(pB, j1 & 63);
                if (pj1 == 0) { jfree = j1; dstar = delta; break; }

                // S from matched-edge cost + v (no LDS dependency)
                float mcj = (j1 < 64) ? readlane_f(mcA, j1) : readlane_f(mcB, j1 & 63);
                float vj  = (j1 < 64) ? readlane_f(vvA, j1) : readlane_f(vvB, j1 & 63);
                cA_f = Tc[(pj1-1)*ST + idxA];
                cB_f = Tc[(pj1-1)*ST + idxB];
                S = (delta - mcj) + vj;
                j0 = j1;
            }

            // prefetch next phase's first row (hidden under update+augment)
            {
                int r1 = dijA ? (int)__ffsll(dijA)
                              : (dijB ? (int)__ffsll(dijB) + 64 : 0);
                if (r1) { pcAf = Tc[(r1-1)*ST + idxA]; pcBf = Tc[(r1-1)*ST + idxB]; }
            }
            if (usedA && jA >= 1) vvA += dpopA - dstar;
            if (usedB)            vvB += dpopB - dstar;

            int jc = jfree;
            for (int s = 0; s <= MM && jc > 0; ++s) {
                int wa = readlane_i(wayA, jc & 63);
                int wb = readlane_i(wayB, jc & 63);
                int w  = (jc < 64) ? wa : wb;
                int pa = readlane_i(pA, w & 63);
                int pb = readlane_i(pB, w & 63);
                int pw = (w < 64) ? pa : pb;
                if (jA == jc) { pA = pw; mcA = Tc[(pw-1)*ST + idxA]; }
                if (validB && jB == jc) { pB = pw; mcB = Tc[(pw-1)*ST + idxB]; }
                jc = w;
            }
        }

        // ---- loss (f64, matches reference arithmetic) ----
        double se = 0.0, bce = 0.0;
        if (jA >= 1 && pA > 0) {
            int rr2 = jA - 1, c = pA - 1;
            float dx = __fsub_rn(px[rr2], tvx[c]);
            float dy = __fsub_rn(py[rr2], tvy[c]);
            se = (double)dx*(double)dx + (double)dy*(double)dy;
            double pcv = (double)pc[rr2];
            pcv = fmin(fmax(pcv, 1e-12), 1.0 - 1e-12);
            double tc = (double)tvc[c];
            bce = -(tc * log(pcv) + (1.0 - tc) * log1p(-pcv));
        }
        if (validB && pB > 0) {
            int rr2 = jB - 1, c = pB - 1;
            float dx = __fsub_rn(px[rr2], tvx[c]);
            float dy = __fsub_rn(py[rr2], tvy[c]);
            se += (double)dx*(double)dx + (double)dy*(double)dy;
            double pcv = (double)pc[rr2];
            pcv = fmin(fmax(pcv, 1e-12), 1.0 - 1e-12);
            double tc = (double)tvc[c];
            bce += -(tc * log(pcv) + (1.0 - tc) * log1p(-pcv));
        }
        for (int m = 1; m < 64; m <<= 1) {
            se  += __shfl_xor(se,  m, 64);
            bce += __shfl_xor(bce, m, 64);
        }
        loss = se / (2.0 * (double)K) + bce / (double)K;
    } else {
        if (wave == 1) return;
    }

    // ---- fold final reduce: last finished block sums & writes out ----
    unsigned old = 0;
    if (lane == 0) {
        wsloss[b] = loss;
        __threadfence();
        old = atomicAdd(counter, 1u);
    }
    unsigned long long lastm = __ballot((lane == 0) && (old == BATCH - 1));
    if (lastm) {
        __threadfence();
        unsigned long long bits =
            atomicCAS((unsigned long long*)&wsloss[lane], 0ull, 0ull);
        double v = __longlong_as_double(bits);
        for (int m = 1; m < 64; m <<= 1) v += __shfl_xor(v, m, 64);
        if (lane == 0) out[0] = (float)(v / (double)BATCH);
    }
}

extern "C" void kernel_launch(void* const* d_in, const int* in_sizes, int n_in,
                              void* d_out, int out_size, void* d_ws, size_t ws_size,
                              hipStream_t stream) {
    const float* pred   = (const float*)d_in[0];
    const float* target = (const float*)d_in[1];
    double*   wsl = (double*)d_ws;                       // 64 doubles
    unsigned* cnt = (unsigned*)((char*)d_ws + 512);      // 4-byte counter
    float*    out = (float*)d_out;
    hipMemsetAsync(cnt, 0, sizeof(unsigned), stream);
    hung_all<<<dim3(BATCH), dim3(128), 0, stream>>>(pred, target, wsl, cnt, out);
}

// Round 10
// 56.104 us; speedup vs baseline: 1.0509x; 1.0053x over previous
//
#include <hip/hip_runtime.h>
#include <math.h>

#define BATCH 64
#define MM 100     // predictions per batch (columns)
#define NN 100     // targets per batch (rows after compaction)
#define ST 101     // padded LDS stride (conflict-free row scans)
#define BIGCLAIM 0x7fffffff
#define SENTK 0xFFFFFFFFu

// ---------- wave-uniform primitives ----------

__device__ __forceinline__ int readlane_i(int v, int lane) {
    return __builtin_amdgcn_readlane(v, lane);
}
__device__ __forceinline__ float readlane_f(float v, int lane) {
    return __int_as_float(__builtin_amdgcn_readlane(__float_as_int(v), lane));
}

// order-preserving float->u32 key; low 7 bits = column index. Truncation
// (127 ulp, ~2^-17 rel) only perturbs near-ties; key_val(k) <= true value.
__device__ __forceinline__ unsigned pack_key(float x, int col) {
    unsigned u = __float_as_uint(x);
    u ^= ((unsigned)((int)u >> 31)) | 0x80000000u;
    return (u & 0xFFFFFF80u) | (unsigned)col;
}
__device__ __forceinline__ float key_val(unsigned k) {
    unsigned u = k & 0xFFFFFF80u;
    u = (u & 0x80000000u) ? (u ^ 0x80000000u) : ~u;
    return __uint_as_float(u);
}

template<int CTRL>
__device__ __forceinline__ unsigned dpp_mov_u32(unsigned x) {
    return (unsigned)__builtin_amdgcn_update_dpp((int)x, (int)x, CTRL, 0xF, 0xF, false);
}
template<int CTRL>
__device__ __forceinline__ unsigned dpp_min_u32(unsigned x) {
    unsigned p = dpp_mov_u32<CTRL>(x);
    return x < p ? x : p;
}
// full-wave64 min broadcast (valid at lane 63; path covers all lanes)
__device__ __forceinline__ unsigned wave_min_u32(unsigned x) {
    x = dpp_min_u32<0xB1>(x);
    x = dpp_min_u32<0x4E>(x);
    x = dpp_min_u32<0x141>(x);
    x = dpp_min_u32<0x140>(x);
    x = dpp_min_u32<0x142>(x);
    x = dpp_min_u32<0x143>(x);
    return (unsigned)readlane_i((int)x, 63);
}
// two smallest keys across the wave (each lane contributes 2 candidates).
// Lane 63's (lo,hi) merges only disjoint coverage sets -> correct there.
template<int CTRL>
__device__ __forceinline__ void min2_step(unsigned &lo, unsigned &hi) {
    unsigned olo = dpp_mov_u32<CTRL>(lo);
    unsigned ohi = dpp_mov_u32<CTRL>(hi);
    unsigned mn  = lo < olo ? lo : olo;
    unsigned mx  = lo < olo ? olo : lo;
    unsigned m2  = hi < ohi ? hi : ohi;
    lo = mn;
    hi = mx < m2 ? mx : m2;
}
__device__ __forceinline__ void wave_min2_u32(unsigned a, unsigned b,
                                              unsigned &k1, unsigned &k2) {
    unsigned lo = a < b ? a : b;
    unsigned hi = a < b ? b : a;
    min2_step<0xB1>(lo, hi);
    min2_step<0x4E>(lo, hi);
    min2_step<0x141>(lo, hi);
    min2_step<0x140>(lo, hi);
    min2_step<0x142>(lo, hi);
    min2_step<0x143>(lo, hi);
    k1 = (unsigned)readlane_i((int)lo, 63);
    k2 = (unsigned)readlane_i((int)hi, 63);
}

// One block (2 waves) per batch. Wave-parallel transposed JV: greedy claim
// (LDS atomicMin) -> 2 ARR sweeps (fused 2-min reduce, row prefetch) ->
// Dijkstra phases (implicit u, matched-edge-cost registers keep the S
// update off the LDS-load chain, phase-row prefetch). Last finished block
// sums all 64 losses and writes out[0] (device-scope atomics).

__global__ __launch_bounds__(128) void hung_all(
        const float* __restrict__ pred, const float* __restrict__ target,
        double* __restrict__ wsloss, unsigned* __restrict__ counter,
        float* __restrict__ out) {
    const int b    = blockIdx.x;
    const int tid  = threadIdx.x;
    const int lane = tid & 63;
    const int wave = tid >> 6;
    const float* P = pred + b * MM * 3;
    const float* T = target + b * NN * 3;

    __shared__ float px[MM], py[MM], pc[MM];
    __shared__ float tvx[NN], tvy[NN], tvc[NN];
    __shared__ float Tc[NN * ST];
    __shared__ int   rmini[NN];
    __shared__ int   claimArr[MM + 1];
    __shared__ int   Ksh;

    float pxA = P[3*lane], pyA = P[3*lane+1];
    float pxB = 0.f, pyB = 0.f;
    const bool colBvalid = (lane + 64 < MM);
    if (colBvalid) { pxB = P[3*(lane+64)]; pyB = P[3*(lane+64)+1]; }

    if (wave == 0) {
        px[lane] = pxA; py[lane] = pyA; pc[lane] = P[3*lane+2];
        if (colBvalid) { px[lane+64]=pxB; py[lane+64]=pyB; pc[lane+64]=P[3*(lane+64)+2]; }
        float cxA=T[3*lane], cyA=T[3*lane+1], ccA=T[3*lane+2];
        bool vA_ = ccA > 0.5f;
        float cxB=0.f, cyB=0.f, ccB=0.f; bool vB_=false;
        if (lane + 64 < NN) {
            cxB=T[3*(lane+64)]; cyB=T[3*(lane+64)+1]; ccB=T[3*(lane+64)+2];
            vB_ = ccB > 0.5f;
        }
        unsigned long long mAv = __ballot(vA_);
        unsigned long long mBv = __ballot(vB_);
        int nA_ = __popcll(mAv);
        int K0  = nA_ + __popcll(mBv);
        unsigned long long below = (1ull << lane) - 1ull;
        if (vA_) { int q = __popcll(mAv & below);       tvx[q]=cxA; tvy[q]=cyA; tvc[q]=ccA; }
        if (vB_) { int q = nA_ + __popcll(mBv & below); tvx[q]=cxB; tvy[q]=cyB; tvc[q]=ccB; }
        if (lane == 0) Ksh = K0;
        claimArr[lane] = BIGCLAIM;
        if (lane + 64 <= MM) claimArr[lane + 64] = BIGCLAIM;
    }
    __syncthreads();
    const int K = Ksh;

    const int jA = lane;                 // column 0..63 (0 = sentinel)
    const int jB = lane + 64;            // column 64..127; valid if <= 100
    const bool validB = (jB <= MM);
    const int idxA = (jA >= 1) ? (jA - 1) : 0;
    const int idxB = validB ? (jB - 1) : (MM - 1);

    double loss = 0.0;
    if (K > 0) {
        float txA = (lane < K)      ? tvx[lane]      : 0.f;
        float tyA = (lane < K)      ? tvy[lane]      : 0.f;
        float txB = (lane + 64 < K) ? tvx[lane + 64] : 0.f;
        float tyB = (lane + 64 < K) ? tvy[lane + 64] : 0.f;

        // ---- cost build (waves split rows) + fused packed row argmin ----
        for (int c = wave; c < K; c += 2) {
            float tx = (c < 64) ? readlane_f(txA, c) : readlane_f(txB, c - 64);
            float ty = (c < 64) ? readlane_f(tyA, c) : readlane_f(tyB, c - 64);
            float dxA = __fsub_rn(pxA, tx), dyA = __fsub_rn(pyA, ty);
            float cA = __fsqrt_rn(__fadd_rn(__fmul_rn(dxA,dxA), __fmul_rn(dyA,dyA)));
            Tc[c*ST + lane] = cA;
            unsigned kB = SENTK;
            if (colBvalid) {
                float dxB = __fsub_rn(pxB, tx), dyB = __fsub_rn(pyB, ty);
                float cB = __fsqrt_rn(__fadd_rn(__fmul_rn(dxB,dxB), __fmul_rn(dyB,dyB)));
                Tc[c*ST + lane + 64] = cB;
                kB = pack_key(cB, lane + 64);
            }
            unsigned kA = pack_key(cA, lane);
            unsigned k = wave_min_u32(kA < kB ? kA : kB);
            if (lane == 0) rmini[c] = (int)(k & 127u);
        }
        __syncthreads();
        if (wave == 1) return;

        // ---- greedy claim: min row index wins each argmin column ----
        int rA_ = lane + 1, rB_ = lane + 65;
        int argA = 0, argB = 0;
        if (lane < K)      { argA = rmini[lane] + 1;      atomicMin(&claimArr[argA], rA_); }
        if (lane + 64 < K) { argB = rmini[lane + 64] + 1; atomicMin(&claimArr[argB], rB_); }
        __threadfence_block();
        int pA = 0, pB = 0;
        if (jA >= 1) { int c0 = claimArr[jA]; pA = (c0 != BIGCLAIM) ? c0 : 0; }
        if (validB)  { int c0 = claimArr[jB]; pB = (c0 != BIGCLAIM) ? c0 : 0; }
        bool freeA = (lane < K)      && (claimArr[argA] != rA_);
        bool freeB = (lane + 64 < K) && (claimArr[argB] != rB_);
        unsigned long long fA = __ballot(freeA);
        unsigned long long fB = __ballot(freeB);

        // matched-edge cost registers
        float mcA = 0.f, mcB = 0.f;
        if (pA > 0) mcA = Tc[(pA-1)*ST + idxA];
        if (pB > 0) mcB = Tc[(pB-1)*ST + idxB];

        float vvA = 0.f, vvB = 0.f;

        // ---- ARR, 2 sweeps: fused 2-min reduce + next-row prefetch ----
        unsigned long long dijA = 0ull, dijB = 0ull;
        for (int sweep = 0; sweep < 2; ++sweep) {
            unsigned long long curA = fA, curB = fB;
            fA = 0ull; fB = 0ull;
            int rr = curA ? (int)__ffsll(curA)
                          : (curB ? (int)__ffsll(curB) + 64 : 0);
            float cA = 0.f, cB = 0.f;
            if (rr) { cA = Tc[(rr-1)*ST + idxA]; cB = Tc[(rr-1)*ST + idxB]; }
            while (curA | curB) {
                int r;
                if (curA) { r = (int)__ffsll(curA);      curA &= curA - 1; }
                else      { r = (int)__ffsll(curB) + 64; curB &= curB - 1; }
                int r2 = curA ? (int)__ffsll(curA)
                              : (curB ? (int)__ffsll(curB) + 64 : r);
                float nxA = Tc[(r2-1)*ST + idxA];     // prefetch next row
                float nxB = Tc[(r2-1)*ST + idxB];

                float rcA = cA - vvA;
                float rcB = cB - vvB;
                unsigned kA = (jA >= 1) ? pack_key(rcA, jA) : SENTK;
                unsigned kB = validB ? pack_key(rcB, jB) : SENTK;
                unsigned k1, k2;
                wave_min2_u32(kA, kB, k1, k2);
                int j1 = (int)(k1 & 127u);
                float dv = fmaxf(key_val(k2) - key_val(k1), 0.f);

                int holder = (j1 < 64) ? readlane_i(pA, j1)
                                       : readlane_i(pB, j1 & 63);
                if (jA == j1)            { vvA -= dv; pA = r; mcA = cA; }
                if (validB && jB == j1)  { vvB -= dv; pB = r; mcB = cB; }
                if (holder != 0) {
                    if (sweep == 0) {
                        if (holder <= 64) fA |= 1ull << (holder - 1);
                        else              fB |= 1ull << (holder - 65);
                    } else {
                        if (holder <= 64) dijA |= 1ull << (holder - 1);
                        else              dijB |= 1ull << (holder - 65);
                    }
                }
                cA = nxA; cB = nxB;
            }
        }

        // ---- Dijkstra phases (implicit u; S via mc/v readlanes only) ----
        const float INF32 = __builtin_inff();
        float pcAf = 0.f, pcBf = 0.f;
        {
            int r0 = dijA ? (int)__ffsll(dijA)
                          : (dijB ? (int)__ffsll(dijB) + 64 : 0);
            if (r0) { pcAf = Tc[(r0-1)*ST + idxA]; pcBf = Tc[(r0-1)*ST + idxB]; }
        }
        while (dijA | dijB) {
            int r;
            if (dijA) { r = (int)__ffsll(dijA);      dijA &= dijA - 1; }
            else      { r = (int)__ffsll(dijB) + 64; dijB &= dijB - 1; }

            float minvA = INF32, minvB = INF32;
            int wayA = 0, wayB = 0;
            bool usedA = (lane == 0), usedB = false;
            float dpopA = 0.f, dpopB = 0.f;
            if (lane == 0) pA = r;       // p[0] = r (augment terminator)
            int j0 = 0, jfree = -1;
            float dstar = 0.f, S = 0.f;
            float cA_f = pcAf, cB_f = pcBf;

            for (int it = 0; it <= MM; ++it) {
                if (jA >= 1 && !usedA) {
                    float t = (cA_f - vvA) + S;
                    if (t < minvA) { minvA = t; wayA = j0; }
                }
                if (validB && !usedB) {
                    float t = (cB_f - vvB) + S;
                    if (t < minvB) { minvB = t; wayB = j0; }
                }
                unsigned kA = (jA >= 1 && !usedA) ? pack_key(minvA, jA) : SENTK;
                unsigned kB = (validB && !usedB) ? pack_key(minvB, jB) : SENTK;
                unsigned k1 = wave_min_u32(kA < kB ? kA : kB);
                int j1 = (int)(k1 & 127u);
                float delta = key_val(k1);

                if (jA == j1) { usedA = true; dpopA = delta; }
                if (jB == j1) { usedB = true; dpopB = delta; }

                int pj1 = (j1 < 64) ? readlane_i(pA, j1)
                                    : readlane_i(pB, j1 & 63);
                if (pj1 == 0) { jfree = j1; dstar = delta; break; }

                // S from matched-edge cost + v (no LDS dependency)
                float mcj = (j1 < 64) ? readlane_f(mcA, j1) : readlane_f(mcB, j1 & 63);
                float vj  = (j1 < 64) ? readlane_f(vvA, j1) : readlane_f(vvB, j1 & 63);
                cA_f = Tc[(pj1-1)*ST + idxA];
                cB_f = Tc[(pj1-1)*ST + idxB];
                S = (delta - mcj) + vj;
                j0 = j1;
            }

            // prefetch next phase's first row (hidden under update+augment)
            {
                int r1 = dijA ? (int)__ffsll(dijA)
                              : (dijB ? (int)__ffsll(dijB) + 64 : 0);
                if (r1) { pcAf = Tc[(r1-1)*ST + idxA]; pcBf = Tc[(r1-1)*ST + idxB]; }
            }
            if (usedA && jA >= 1) vvA += dpopA - dstar;
            if (usedB)            vvB += dpopB - dstar;

            int jc = jfree;
            for (int s = 0; s <= MM && jc > 0; ++s) {
                int wa = readlane_i(wayA, jc & 63);
                int wb = readlane_i(wayB, jc & 63);
                int w  = (jc < 64) ? wa : wb;
                int pa = readlane_i(pA, w & 63);
                int pb = readlane_i(pB, w & 63);
                int pw = (w < 64) ? pa : pb;
                if (jA == jc) { pA = pw; mcA = Tc[(pw-1)*ST + idxA]; }
                if (validB && jB == jc) { pB = pw; mcB = Tc[(pw-1)*ST + idxB]; }
                jc = w;
            }
        }

        // ---- loss (f64, matches reference arithmetic) ----
        double se = 0.0, bce = 0.0;
        if (jA >= 1 && pA > 0) {
            int rr2 = jA - 1, c = pA - 1;
            float dx = __fsub_rn(px[rr2], tvx[c]);
            float dy = __fsub_rn(py[rr2], tvy[c]);
            se = (double)dx*(double)dx + (double)dy*(double)dy;
            double pcv = (double)pc[rr2];
            pcv = fmin(fmax(pcv, 1e-12), 1.0 - 1e-12);
            double tc = (double)tvc[c];
            bce = -(tc * log(pcv) + (1.0 - tc) * log1p(-pcv));
        }
        if (validB && pB > 0) {
            int rr2 = jB - 1, c = pB - 1;
            float dx = __fsub_rn(px[rr2], tvx[c]);
            float dy = __fsub_rn(py[rr2], tvy[c]);
            se += (double)dx*(double)dx + (double)dy*(double)dy;
            double pcv = (double)pc[rr2];
            pcv = fmin(fmax(pcv, 1e-12), 1.0 - 1e-12);
            double tc = (double)tvc[c];
            bce += -(tc * log(pcv) + (1.0 - tc) * log1p(-pcv));
        }
        for (int m = 1; m < 64; m <<= 1) {
            se  += __shfl_xor(se,  m, 64);
            bce += __shfl_xor(bce, m, 64);
        }
        loss = se / (2.0 * (double)K) + bce / (double)K;
    } else {
        if (wave == 1) return;
    }

    // ---- fold final reduce: last finished block sums & writes out ----
    unsigned old = 0;
    if (lane == 0) {
        wsloss[b] = loss;
        __threadfence();
        old = atomicAdd(counter, 1u);
    }
    unsigned long long lastm = __ballot((lane == 0) && (old == BATCH - 1));
    if (lastm) {
        __threadfence();
        unsigned long long bits =
            atomicCAS((unsigned long long*)&wsloss[lane], 0ull, 0ull);
        double v = __longlong_as_double(bits);
        for (int m = 1; m < 64; m <<= 1) v += __shfl_xor(v, m, 64);
        if (lane == 0) out[0] = (float)(v / (double)BATCH);
    }
}

extern "C" void kernel_launch(void* const* d_in, const int* in_sizes, int n_in,
                              void* d_out, int out_size, void* d_ws, size_t ws_size,
                              hipStream_t stream) {
    const float* pred   = (const float*)d_in[0];
    const float* target = (const float*)d_in[1];
    double*   wsl = (double*)d_ws;                       // 64 doubles
    unsigned* cnt = (unsigned*)((char*)d_ws + 512);      // 4-byte counter
    float*    out = (float*)d_out;
    hipMemsetAsync(cnt, 0, sizeof(unsigned), stream);
    hung_all<<<dim3(BATCH), dim3(128), 0, stream>>>(pred, target, wsl, cnt, out);
}